// Round 5
// baseline (1566.518 us; speedup 1.0000x reference)
//
#include <hip/hip_runtime.h>
#include <math.h>

#define NN 50000
#define NE 400000

typedef _Float16 f16;
typedef _Float16 f16x8 __attribute__((ext_vector_type(8)));
typedef _Float16 f16x4 __attribute__((ext_vector_type(4)));
typedef _Float16 f16x2 __attribute__((ext_vector_type(2)));
typedef float f32x4 __attribute__((ext_vector_type(4)));

static __device__ __forceinline__ float dot8(f16x8 a, f16x8 b, float acc) {
#if defined(__has_builtin) && __has_builtin(__builtin_amdgcn_fdot2)
#pragma unroll
  for (int j = 0; j < 4; ++j) {
    f16x2 x = {a[2 * j], a[2 * j + 1]};
    f16x2 y = {b[2 * j], b[2 * j + 1]};
    acc = __builtin_amdgcn_fdot2(x, y, acc, false);
  }
#else
#pragma unroll
  for (int j = 0; j < 8; ++j) acc += (float)a[j] * (float)b[j];
#endif
  return acc;
}

// ================= MFMA fp16 GEMM =================
// A [M][lda] f16 (A2: optional second source for kc>=128, same lda), WT [Ntot][K] f16.
// fresid: fused epilogue -> outb = relu(acc + outf(read) + fresid), f16.
__global__ __launch_bounds__(256) void hgemm_kernel(
    const f16* __restrict__ A, int lda, const f16* __restrict__ A2,
    const f16* __restrict__ WT, int K,
    const float* __restrict__ bias,
    const float* __restrict__ rowscale,
    float* __restrict__ outf, int ldf,
    f16* __restrict__ outb, int ldb,
    int split_col, int M, int beta,
    int zA, int zW, int zB,
    const f16* __restrict__ fresid)
{
  __shared__ f16 As[128 * 128];
  __shared__ f16 Bs[64 * 128];
  const int t = threadIdx.x;
  const int wv = t >> 6, lane = t & 63;
  const int l15 = lane & 15, l4 = lane >> 4;
  const int row0 = blockIdx.x * 128;
  const int col0 = blockIdx.y * 64;
  const int z = blockIdx.z;
  A  += (size_t)z * zA;
  WT += (size_t)z * zW;

  f32x4 acc[2][4];
#pragma unroll
  for (int m = 0; m < 2; ++m)
#pragma unroll
    for (int n = 0; n < 4; ++n) acc[m][n] = (f32x4){0.f, 0.f, 0.f, 0.f};

  for (int kc = 0; kc < K; kc += 128) {
    const f16* Ap = (A2 && kc >= 128) ? A2 : A;
    const int koff = (A2 && kc >= 128) ? kc - 128 : kc;
    for (int i = t; i < 2048; i += 256) {
      int r = i >> 4, c8 = i & 15;
      int gr = row0 + r;
      float4 v = make_float4(0.f, 0.f, 0.f, 0.f);
      if (gr < M) v = *(const float4*)(Ap + (size_t)gr * lda + koff + c8 * 8);
      *(float4*)(As + r * 128 + ((c8 ^ (r & 15)) << 3)) = v;
    }
    for (int i = t; i < 1024; i += 256) {
      int c = i >> 4, c8 = i & 15;
      float4 v = *(const float4*)(WT + (size_t)(col0 + c) * K + kc + c8 * 8);
      *(float4*)(Bs + c * 128 + ((c8 ^ (c & 15)) << 3)) = v;
    }
    __syncthreads();
#pragma unroll
    for (int ks = 0; ks < 4; ++ks) {
      const int co = (((ks * 4 + l4) ^ l15) << 3);
      f16x8 a0 = *(const f16x8*)(As + (wv * 32 +      l15) * 128 + co);
      f16x8 a1 = *(const f16x8*)(As + (wv * 32 + 16 + l15) * 128 + co);
      f16x8 b0 = *(const f16x8*)(Bs + (     l15) * 128 + co);
      f16x8 b1 = *(const f16x8*)(Bs + (16 + l15) * 128 + co);
      f16x8 b2 = *(const f16x8*)(Bs + (32 + l15) * 128 + co);
      f16x8 b3 = *(const f16x8*)(Bs + (48 + l15) * 128 + co);
      acc[0][0] = __builtin_amdgcn_mfma_f32_16x16x32_f16(a0, b0, acc[0][0], 0, 0, 0);
      acc[0][1] = __builtin_amdgcn_mfma_f32_16x16x32_f16(a0, b1, acc[0][1], 0, 0, 0);
      acc[0][2] = __builtin_amdgcn_mfma_f32_16x16x32_f16(a0, b2, acc[0][2], 0, 0, 0);
      acc[0][3] = __builtin_amdgcn_mfma_f32_16x16x32_f16(a0, b3, acc[0][3], 0, 0, 0);
      acc[1][0] = __builtin_amdgcn_mfma_f32_16x16x32_f16(a1, b0, acc[1][0], 0, 0, 0);
      acc[1][1] = __builtin_amdgcn_mfma_f32_16x16x32_f16(a1, b1, acc[1][1], 0, 0, 0);
      acc[1][2] = __builtin_amdgcn_mfma_f32_16x16x32_f16(a1, b2, acc[1][2], 0, 0, 0);
      acc[1][3] = __builtin_amdgcn_mfma_f32_16x16x32_f16(a1, b3, acc[1][3], 0, 0, 0);
    }
    __syncthreads();
  }

  float bv4[4];
#pragma unroll
  for (int n = 0; n < 4; ++n) bv4[n] = bias ? bias[col0 + n * 16 + l15] : 0.f;
#pragma unroll
  for (int m = 0; m < 2; ++m) {
#pragma unroll
    for (int j = 0; j < 4; ++j) {
      int r = row0 + wv * 32 + m * 16 + l4 * 4 + j;
      if (r >= M) continue;
      float rsv = rowscale ? rowscale[r] : 1.f;
#pragma unroll
      for (int n = 0; n < 4; ++n) {
        int c = col0 + n * 16 + l15;
        float val = acc[m][n][j] * rsv + bv4[n];
        if (fresid) {
          val += outf[(size_t)r * ldf + c] + (float)fresid[(size_t)r * 128 + c];
          outb[(size_t)r * ldb + c] = (f16)fmaxf(val, 0.f);
        } else if (c < split_col) {
          outb[(size_t)r * ldb + (size_t)z * zB + c] = (f16)val;
        } else {
          float* p = outf + (size_t)r * ldf + (c - split_col);
          *p = (beta ? *p : 0.f) + val;
        }
      }
    }
  }
}

// ================= CSR build =================
__global__ void zero_int_kernel(int* __restrict__ p, int n) {
  int i = blockIdx.x * 256 + threadIdx.x;
  if (i < n) p[i] = 0;
}
__global__ void hist_kernel(const int* __restrict__ dst, int* __restrict__ deg) {
  int e = blockIdx.x * 256 + threadIdx.x;
  if (e < NE) atomicAdd(&deg[dst[e]], 1);
}
__global__ void scanA_kernel(const int* __restrict__ deg, int* __restrict__ rowstart,
                             int* __restrict__ part) {
  __shared__ int sd[256];
  int b = blockIdx.x, t = threadIdx.x, i = b * 256 + t;
  sd[t] = (i < NN) ? deg[i] : 0;
  __syncthreads();
  for (int o = 1; o < 256; o <<= 1) {
    int v = (t >= o) ? sd[t - o] : 0;
    __syncthreads();
    sd[t] += v;
    __syncthreads();
  }
  if (i < NN) rowstart[i + 1] = sd[t];
  if (t == 255) part[b] = sd[255];
}
__global__ void scanB_kernel(int* __restrict__ part, int nb) {
  __shared__ int sd[256];
  int t = threadIdx.x;
  sd[t] = (t < nb) ? part[t] : 0;
  __syncthreads();
  for (int o = 1; o < 256; o <<= 1) {
    int v = (t >= o) ? sd[t - o] : 0;
    __syncthreads();
    sd[t] += v;
    __syncthreads();
  }
  if (t < nb) part[t] = sd[t];
}
__global__ void scanC_kernel(const int* __restrict__ deg, int* __restrict__ rowstart,
                             const int* __restrict__ part, int* __restrict__ cursor) {
  int b = blockIdx.x, t = threadIdx.x, i = b * 256 + t;
  if (i >= NN) return;
  int off = b ? part[b - 1] : 0;
  int fin = rowstart[i + 1] + off;
  rowstart[i + 1] = fin;
  cursor[i] = fin - deg[i];
  if (i == 0) rowstart[0] = 0;
}
__global__ void scatter_kernel(const int* __restrict__ dst, const int* __restrict__ src,
                               const float* __restrict__ dirw, const float* __restrict__ geo,
                               int* __restrict__ cursor,
                               int* __restrict__ srcp, f16* __restrict__ dirpb,
                               f16* __restrict__ geop) {
  int e = blockIdx.x * 256 + threadIdx.x;
  if (e < NE) {
    int pos = atomicAdd(&cursor[dst[e]], 1);
    srcp[pos] = src[e];
    float dv = dirw[e];
    dirpb[pos] = (f16)dv;
    f16* gp = geop + (size_t)pos * 24;
#pragma unroll
    for (int j = 0; j < 20; ++j) gp[j] = (f16)geo[(size_t)e * 20 + j];
    gp[20] = (f16)dv;
    gp[21] = (f16)0.f; gp[22] = (f16)0.f; gp[23] = (f16)0.f;
  }
}
__global__ void swc_kernel(const int* __restrict__ deg, float* __restrict__ swc) {
  int n = blockIdx.x * 256 + threadIdx.x;
  if (n < NN) swc[n] = deg[n] ? 1.0f : 0.0f;
}

// ================= per-layer weight prep (batched over 3 layers) =================
__global__ void prep_kernel(const float* __restrict__ Wee, const float* __restrict__ bee,
                            const float* __restrict__ WeAll, const float* __restrict__ beAll,
                            float* __restrict__ matsAll)
{
  const int layer = blockIdx.y;
  const float* We = WeAll + (size_t)layer * 49152;
  const float* be = beAll + (size_t)layer * 384;
  float* mats = matsAll + (size_t)layer * 132352;
  int idx = blockIdx.x * 256 + threadIdx.x;
  if (idx >= 132352) return;
  float acc = 0.0f;
  if (idx < 49152) {
    int h = idx >> 14, rem = idx & 16383, c = rem >> 7, u = rem & 127;
    for (int j = 0; j < 128; ++j)
      acc += We[(size_t)j * 384 + h * 128 + c] * Wee[(size_t)(128 + u) * 128 + j];
    mats[idx] = acc;
  } else if (idx < 58368) {
    int r = idx - 49152; int h = r / 3072; int rem = r - h * 3072; int c = rem / 24; int u = rem - c * 24;
    if (u < 21) {
      int trow = (u < 20) ? (257 + u) : 256;
      for (int j = 0; j < 128; ++j)
        acc += We[(size_t)j * 384 + h * 128 + c] * Wee[(size_t)trow * 128 + j];
    }
    mats[idx] = acc;
  } else if (idx < 107520) {
    int r = idx - 58368; int h = r >> 14; int rem = r & 16383; int tt = rem >> 7; int c = rem & 127;
    for (int j = 0; j < 128; ++j)
      acc += Wee[(size_t)(128 + tt) * 128 + j] * We[(size_t)j * 384 + h * 128 + c];
    mats[idx] = acc;
  } else if (idx < 115584) {
    int r = idx - 107520; int h = r / 2688; int rem = r - h * 2688; int tt = rem >> 7; int c = rem & 127;
    int trow = (tt < 20) ? (257 + tt) : 256;
    for (int j = 0; j < 128; ++j)
      acc += Wee[(size_t)trow * 128 + j] * We[(size_t)j * 384 + h * 128 + c];
    mats[idx] = acc;
  } else if (idx < 115968) {
    int r = idx - 115584; int h = r >> 7; int c = r & 127;
    for (int j = 0; j < 128; ++j)
      acc += bee[j] * We[(size_t)j * 384 + h * 128 + c];
    mats[idx] = acc + be[h * 128 + c];
  } else {
    int r = idx - 115968; int tt = r >> 7; int c = r & 127;
    for (int j = 0; j < 128; ++j)
      acc += Wee[(size_t)tt * 128 + j] *
             (We[(size_t)j * 384 + c] + We[(size_t)j * 384 + 128 + c] + We[(size_t)j * 384 + 256 + c]);
    mats[idx] = acc * (1.0f / 3.0f);
  }
}

// f16 transposed copies: M2T_f[3l][3h][128u][128k], W2allT_f[3l][128c][512k], Ws0T_f[3l][128c][128k]
__global__ void prep2_kernel(const float* __restrict__ matsAll, f16* __restrict__ M2T_f,
                             f16* __restrict__ W2allT_f, f16* __restrict__ Ws0T_f)
{
  const int y = blockIdx.y;
  const float* my = matsAll + (size_t)y * 132352;
  int idx = blockIdx.x * 256 + threadIdx.x;
  if (idx < 49152) {
    int h = idx >> 14, r = idx & 16383, u = r >> 7, k = r & 127;
    M2T_f[y * 49152 + idx] = (f16)my[h * 16384 + k * 128 + u];
  } else if (idx < 114688) {
    int r = idx - 49152;
    int c = r >> 9, k = r & 511;
    float v = 0.f;
    if (k < 384) {
      int h = k >> 7, tt = k & 127;
      v = my[58368 + h * 16384 + tt * 128 + c];
    } else if (k < 456) {
      int q = k - 384; int h = q / 24; int tt = q - h * 24;
      if (tt < 21)       v = my[107520 + h * 2688 + tt * 128 + c];
      else if (tt == 21) v = my[115584 + h * 128 + c];
    }
    W2allT_f[y * 65536 + r] = (f16)v;
  } else if (idx < 131072) {
    int r = idx - 114688; int c = r >> 7, k = r & 127;
    Ws0T_f[y * 16384 + r] = (f16)my[115968 + k * 128 + c];
  }
}

// build f16 WT for the big GEMMs + concatenated bias
__global__ void wprep_kernel(const float* __restrict__ Wq, const float* __restrict__ Wk,
                             const float* __restrict__ Wv, const float* __restrict__ Ws,
                             const float* __restrict__ Wres, const float* __restrict__ Wctr,
                             const float* __restrict__ bq, const float* __restrict__ bk,
                             const float* __restrict__ bv, const float* __restrict__ bs,
                             f16* __restrict__ WTcat, f16* __restrict__ WresT,
                             f16* __restrict__ WctrT2, float* __restrict__ biascat)
{
  int idx = blockIdx.x * 256 + threadIdx.x;
  if (idx < 491520) {
    int i = idx / 163840; int r = idx % 163840; int c = r >> 7; int k = r & 127;
    float v;
    if (c < 384)       v = Wq[((size_t)i * 128 + k) * 384 + c];
    else if (c < 768)  v = Wk[((size_t)i * 128 + k) * 384 + (c - 384)];
    else if (c < 1152) v = Wv[((size_t)i * 128 + k) * 384 + (c - 768)];
    else               v = Ws[((size_t)i * 128 + k) * 128 + (c - 1152)];
    WTcat[idx] = (f16)v;
  } else if (idx < 507904) {
    int r = idx - 491520; int c = r >> 7, k = r & 127;
    WresT[r] = (f16)Wres[k * 128 + c];
  } else if (idx < 540672) {          // WctrT2[c][k(256)] = Wctr[k][c]
    int r = idx - 507904; int c = r >> 8, k = r & 255;
    WctrT2[r] = (f16)Wctr[(size_t)k * 128 + c];
  } else if (idx < 544512) {
    int r = idx - 540672; int i = r / 1280; int c = r % 1280;
    float v;
    if (c < 384)       v = bq[i * 384 + c];
    else if (c < 768)  v = bk[i * 384 + (c - 384)];
    else if (c < 1152) v = bv[i * 384 + (c - 768)];
    else               v = bs[i * 128 + (c - 1152)];
    biascat[r] = v;
  }
}

// ================= g34 = q_h @ M34T  [N][3][24] =================
__global__ __launch_bounds__(256) void g34_kernel(const f16* __restrict__ qkv,
                                                  const float* __restrict__ mats,
                                                  f16* __restrict__ g34b)
{
  __shared__ float xs[32][128];
  const int y = blockIdx.y;
  const float* M34T = mats + 49152 + y * 3072;
  const int n0 = blockIdx.x * 32;
  const int t = threadIdx.x;
  for (int idx = t; idx < 4096; idx += 256) {
    int rr = idx >> 7, kk = idx & 127;
    int n = n0 + rr;
    xs[rr][kk] = (n < NN) ? (float)qkv[(size_t)n * 1280 + y * 128 + kk] : 0.f;
  }
  __syncthreads();
  const int rr = t >> 3;
  const int ub = (t & 7) * 3;
  float a0 = 0.f, a1 = 0.f, a2 = 0.f;
  for (int k = 0; k < 128; ++k) {
    float x = xs[rr][k];
    const float* w = M34T + k * 24 + ub;
    a0 = fmaf(x, w[0], a0); a1 = fmaf(x, w[1], a1); a2 = fmaf(x, w[2], a2);
  }
  int n = n0 + rr;
  if (n < NN) {
    size_t b = ((size_t)n * 3 + y) * 24 + ub;
    g34b[b] = (f16)a0; g34b[b + 1] = (f16)a1; g34b[b + 2] = (f16)a2;
  }
}

// ================= attention v3: packed row [q|k|v|h0], 2-deep pipelined edges ============
struct EdgeRegs {
  f16x8 k0, k1, k2, v0, v1, v2, h0;
  float d, gea, geb;
};

static __device__ __forceinline__ EdgeRegs load_edge(
    const f16* __restrict__ qkv, const int* __restrict__ srcp,
    const f16* __restrict__ dirpb, const f16* __restrict__ geop,
    int ii, int sl)
{
  EdgeRegs E;
  const int s = srcp[ii];
  E.d = (float)dirpb[ii];
  const f16* kp = qkv + (size_t)s * 1280 + sl * 8;
  E.k0 = *(const f16x8*)(kp + 384);
  E.k1 = *(const f16x8*)(kp + 512);
  E.k2 = *(const f16x8*)(kp + 640);
  E.v0 = *(const f16x8*)(kp + 768);
  E.v1 = *(const f16x8*)(kp + 896);
  E.v2 = *(const f16x8*)(kp + 1024);
  E.h0 = *(const f16x8*)(kp + 1152);
  E.gea = (float)geop[(size_t)ii * 24 + sl];
  E.geb = (sl < 8) ? (float)geop[(size_t)ii * 24 + 16 + sl] : 0.f;
  return E;
}

__global__ __launch_bounds__(256) void attn_kernel(
    const f16* __restrict__ qkv,
    f16* __restrict__ g2all,
    const f16* __restrict__ g34b,
    const int* __restrict__ rowstart,
    const int* __restrict__ srcp,
    const f16* __restrict__ dirpb,
    const f16* __restrict__ geop,
    float* __restrict__ tmp1)
{
  const int sl = threadIdx.x & 15;
  const int n = blockIdx.x * 16 + (threadIdx.x >> 4);
  const float rsC = 0.088388347648318447f;  // 1/sqrt(128)

  const size_t qbase = (size_t)n * 1280 + sl * 8;
  f16x8 qv0 = *(const f16x8*)(qkv + qbase);
  f16x8 qv1 = *(const f16x8*)(qkv + qbase + 128);
  f16x8 qv2 = *(const f16x8*)(qkv + qbase + 256);
  const size_t g2base = (size_t)n * 512 + sl * 8;
  f16x8 ga0 = *(const f16x8*)(g2all + g2base);
  f16x8 ga1 = *(const f16x8*)(g2all + g2base + 128);
  f16x8 ga2 = *(const f16x8*)(g2all + g2base + 256);
  float g34a[3], g34c[3];
#pragma unroll
  for (int h = 0; h < 3; ++h) {
    g34a[h] = (float)g34b[((size_t)n * 3 + h) * 24 + sl];
    g34c[h] = (sl < 8) ? (float)g34b[((size_t)n * 3 + h) * 24 + 16 + sl] : 0.f;
  }
  float den0 = 0.f, den1 = 0.f, den2 = 0.f;
  float F2[3][8], av[3][8];
#pragma unroll
  for (int h = 0; h < 3; ++h)
#pragma unroll
    for (int j = 0; j < 8; ++j) { F2[h][j] = 0.f; av[h][j] = 0.f; }
  float f34a0 = 0.f, f34a1 = 0.f, f34a2 = 0.f;
  float f34c0 = 0.f, f34c1 = 0.f, f34c2 = 0.f;

  const int beg = rowstart[n], end = rowstart[n + 1];
  if (beg < end) {
    EdgeRegs cur = load_edge(qkv, srcp, dirpb, geop, beg, sl);
    for (int ii = beg; ii < end; ++ii) {
      const int jn = (ii + 1 < end) ? ii + 1 : ii;
      EdgeRegs nxt = load_edge(qkv, srcp, dirpb, geop, jn, sl);

      float pa0 = dot8(qv0, cur.k0, 0.f) + cur.d * dot8(ga0, cur.h0, 0.f)
                + cur.gea * g34a[0] + cur.geb * g34c[0];
      float pa1 = dot8(qv1, cur.k1, 0.f) + cur.d * dot8(ga1, cur.h0, 0.f)
                + cur.gea * g34a[1] + cur.geb * g34c[1];
      float pa2 = dot8(qv2, cur.k2, 0.f) + cur.d * dot8(ga2, cur.h0, 0.f)
                + cur.gea * g34a[2] + cur.geb * g34c[2];
#pragma unroll
      for (int off = 1; off < 16; off <<= 1) {
        pa0 += __shfl_xor(pa0, off);
        pa1 += __shfl_xor(pa1, off);
        pa2 += __shfl_xor(pa2, off);
      }
      const float w0 = __expf(pa0 * rsC);
      const float w1 = __expf(pa1 * rsC);
      const float w2 = __expf(pa2 * rsC);
      den0 += w0; den1 += w1; den2 += w2;
      const float wd0 = w0 * cur.d, wd1 = w1 * cur.d, wd2 = w2 * cur.d;
#pragma unroll
      for (int j = 0; j < 8; ++j) {
        const float hf = (float)cur.h0[j];
        F2[0][j] = fmaf(wd0, hf, F2[0][j]);
        F2[1][j] = fmaf(wd1, hf, F2[1][j]);
        F2[2][j] = fmaf(wd2, hf, F2[2][j]);
        av[0][j] = fmaf(w0, (float)cur.v0[j], av[0][j]);
        av[1][j] = fmaf(w1, (float)cur.v1[j], av[1][j]);
        av[2][j] = fmaf(w2, (float)cur.v2[j], av[2][j]);
      }
      f34a0 = fmaf(w0, cur.gea, f34a0); f34a1 = fmaf(w1, cur.gea, f34a1); f34a2 = fmaf(w2, cur.gea, f34a2);
      f34c0 = fmaf(w0, cur.geb, f34c0); f34c1 = fmaf(w1, cur.geb, f34c1); f34c2 = fmaf(w2, cur.geb, f34c2);
      cur = nxt;
    }
  }

  float sc[3], swh[3], dens[3] = {den0, den1, den2};
  float f34av[3] = {f34a0, f34a1, f34a2}, f34cv[3] = {f34c0, f34c1, f34c2};
#pragma unroll
  for (int h = 0; h < 3; ++h) {
    sc[h] = (1.f / 3.f) / (dens[h] + 1e-16f);
    swh[h] = dens[h] * sc[h];
  }
#pragma unroll
  for (int h = 0; h < 3; ++h) {
    f16x8 o;
#pragma unroll
    for (int j = 0; j < 8; ++j) o[j] = (f16)(F2[h][j] * sc[h]);
    *(f16x8*)(g2all + g2base + h * 128) = o;
  }
#pragma unroll
  for (int h = 0; h < 3; ++h) {
    g2all[(size_t)n * 512 + 384 + h * 24 + sl] = (f16)(f34av[h] * sc[h]);
    if (sl < 8) {
      float fcv = (sl == 5) ? swh[h] : f34cv[h] * sc[h];
      g2all[(size_t)n * 512 + 384 + h * 24 + 16 + sl] = (f16)fcv;
    }
  }
  float* tp = tmp1 + (size_t)n * 128 + sl * 8;
  float4 t0 = *(float4*)tp;
  float4 t1 = *(float4*)(tp + 4);
  t0.x += av[0][0] * sc[0] + av[1][0] * sc[1] + av[2][0] * sc[2];
  t0.y += av[0][1] * sc[0] + av[1][1] * sc[1] + av[2][1] * sc[2];
  t0.z += av[0][2] * sc[0] + av[1][2] * sc[1] + av[2][2] * sc[2];
  t0.w += av[0][3] * sc[0] + av[1][3] * sc[1] + av[2][3] * sc[2];
  t1.x += av[0][4] * sc[0] + av[1][4] * sc[1] + av[2][4] * sc[2];
  t1.y += av[0][5] * sc[0] + av[1][5] * sc[1] + av[2][5] * sc[2];
  t1.z += av[0][6] * sc[0] + av[1][6] * sc[1] + av[2][6] * sc[2];
  t1.w += av[0][7] * sc[0] + av[1][7] * sc[1] + av[2][7] * sc[2];
  *(float4*)tp = t0;
  *(float4*)(tp + 4) = t1;
}

// ================= h f32 -> f16 (hb + qkvh h0-cols) =================
__global__ void hconv_kernel(const float* __restrict__ src, f16* __restrict__ hb,
                             f16* __restrict__ qkvh) {
  int i = blockIdx.x * 256 + threadIdx.x;
  if (i >= NN * 32) return;
  float4 a = ((const float4*)src)[i];
  f16x4 o;
  o[0] = (f16)a.x; o[1] = (f16)a.y; o[2] = (f16)a.z; o[3] = (f16)a.w;
  ((f16x4*)hb)[i] = o;
  int r = i >> 5, c4 = i & 31;
  *(f16x4*)(qkvh + (size_t)r * 1280 + 1152 + c4 * 4) = o;
}

// ================= launch =================
extern "C" void kernel_launch(void* const* d_in, const int* in_sizes, int n_in,
                              void* d_out, int out_size, void* d_ws, size_t ws_size,
                              hipStream_t stream)
{
  (void)in_sizes; (void)n_in; (void)out_size; (void)ws_size;
  const float* h    = (const float*)d_in[0];
  const float* geo  = (const float*)d_in[1];
  const float* dirw = (const float*)d_in[2];
  const int*   src  = (const int*)d_in[3];
  const int*   dst  = (const int*)d_in[4];
  const float* Wee  = (const float*)d_in[5];
  const float* bee  = (const float*)d_in[6];
  const float* Wres = (const float*)d_in[7];
  const float* bres = (const float*)d_in[8];
  const float* Wq   = (const float*)d_in[9];
  const float* bq   = (const float*)d_in[10];
  const float* Wk   = (const float*)d_in[11];
  const float* bk   = (const float*)d_in[12];
  const float* Wv   = (const float*)d_in[13];
  const float* bv   = (const float*)d_in[14];
  const float* We   = (const float*)d_in[15];
  const float* be   = (const float*)d_in[16];
  const float* Ws   = (const float*)d_in[17];
  const float* bs   = (const float*)d_in[18];
  const float* Wctr = (const float*)d_in[19];
  const float* bctr = (const float*)d_in[20];
  float* tmp1 = (float*)d_out;     // d_out doubles as per-layer fp32 accumulator

  char* base = (char*)d_ws;
  size_t off = 0;
  auto take = [&](size_t bytes) -> char* {
    char* p = base + off;
    off += bytes;
    off = (off + 255) & ~(size_t)255;
    return p;
  };
  f16* qkvh     = (f16*)take((size_t)NN * 1280 * 2);   // [q|k|v|h0]
  f16* g2all    = (f16*)take((size_t)NN * 512 * 2);
  f16* g34b     = (f16*)take((size_t)NN * 72 * 2);
  f16* hb       = (f16*)take((size_t)NN * 128 * 2);
  f16* xb1      = (f16*)take((size_t)NN * 128 * 2);
  f16* xb2      = (f16*)take((size_t)NN * 128 * 2);
  float* mats   = (float*)take((size_t)3 * 132352 * 4);
  f16* M2T_f    = (f16*)take((size_t)3 * 49152 * 2);
  f16* W2allT_f = (f16*)take((size_t)3 * 65536 * 2);
  f16* Ws0T_f   = (f16*)take((size_t)3 * 16384 * 2);
  f16* WTcat    = (f16*)take(491520 * 2);
  f16* WresT    = (f16*)take(16384 * 2);
  f16* WctrT2   = (f16*)take(32768 * 2);
  float* biascat = (float*)take(3840 * 4);
  float* swc    = (float*)take((size_t)NN * 4);
  f16* dirpb    = (f16*)take((size_t)NE * 2);
  f16* geop     = (f16*)take((size_t)NE * 24 * 2);
  int* deg      = (int*)take((size_t)NN * 4);
  int* rowstart = (int*)take((size_t)(NN + 1) * 4);
  int* cursor   = (int*)take((size_t)NN * 4);
  int* srcp     = (int*)take((size_t)NE * 4);
  int* part     = (int*)take(256 * 4);

  // CSR by dst
  zero_int_kernel<<<(NN + 255) / 256, 256, 0, stream>>>(deg, NN);
  hist_kernel<<<(NE + 255) / 256, 256, 0, stream>>>(dst, deg);
  scanA_kernel<<<196, 256, 0, stream>>>(deg, rowstart, part);
  scanB_kernel<<<1, 256, 0, stream>>>(part, 196);
  scanC_kernel<<<196, 256, 0, stream>>>(deg, rowstart, part, cursor);
  scatter_kernel<<<(NE + 255) / 256, 256, 0, stream>>>(dst, src, dirw, geo, cursor,
                                                       srcp, dirpb, geop);
  swc_kernel<<<(NN + 255) / 256, 256, 0, stream>>>(deg, swc);
  hconv_kernel<<<6250, 256, 0, stream>>>(h, hb, qkvh);
  wprep_kernel<<<(544512 + 255) / 256, 256, 0, stream>>>(Wq, Wk, Wv, Ws, Wres, Wctr,
                                                         bq, bk, bv, bs,
                                                         WTcat, WresT, WctrT2, biascat);
  prep_kernel<<<dim3(518, 3), 256, 0, stream>>>(Wee, bee, We, be, mats);
  prep2_kernel<<<dim3(512, 3), 256, 0, stream>>>(mats, M2T_f, W2allT_f, Ws0T_f);
  zero_int_kernel<<<(NN * 256 + 255) / 256, 256, 0, stream>>>((int*)g2all, NN * 256);

  // layer-0 residual (f16) -> xb2
  hgemm_kernel<<<dim3(391, 2, 1), 256, 0, stream>>>(hb, 128, nullptr, WresT, 128, bres, nullptr,
      nullptr, 0, xb2, 128, 1 << 30, NN, 0, 0, 0, 0, nullptr);

  const f16* xin = hb;
  for (int i = 0; i < 3; ++i) {
    // fat: [q|k|v] -> qkvh cols 0..1151 (f16), skip -> tmp1 (f32, fresh)
    hgemm_kernel<<<dim3(391, 20, 1), 256, 0, stream>>>(xin, 128, nullptr,
        WTcat + (size_t)i * 163840, 128, biascat + i * 1280, nullptr,
        tmp1, 128, qkvh, 1280, 1152, NN, 0, 0, 0, 0, nullptr);
    // tmp1 += mask * (h @ Wsum0)
    hgemm_kernel<<<dim3(391, 2, 1), 256, 0, stream>>>(hb, 128, nullptr,
        Ws0T_f + (size_t)i * 16384, 128, nullptr, swc, tmp1, 128,
        nullptr, 0, 0, NN, 1, 0, 0, 0, nullptr);
    // g2 per head (z-batched) -> g2all cols 0..383
    hgemm_kernel<<<dim3(391, 2, 3), 256, 0, stream>>>(qkvh, 1280, nullptr,
        M2T_f + (size_t)i * 49152, 128, nullptr, nullptr, nullptr, 0,
        g2all, 512, 1 << 30, NN, 0, 128, 16384, 128, nullptr);
    g34_kernel<<<dim3(1563, 3), 256, 0, stream>>>(qkvh, mats + (size_t)i * 132352, g34b);
    attn_kernel<<<3125, 256, 0, stream>>>(qkvh, g2all, g34b, rowstart, srcp,
                                          dirpb, geop, tmp1);
    // fused: xout = relu(fs2fg @ W2all + tmp1 + resid), f16
    const f16* resid = (i == 0) ? xb2 : xin;
    f16* xout = (i == 1) ? xb2 : xb1;
    hgemm_kernel<<<dim3(391, 2, 1), 256, 0, stream>>>(g2all, 512, nullptr,
        W2allT_f + (size_t)i * 65536, 512, nullptr, nullptr, tmp1, 128,
        xout, 128, 0, NN, 0, 0, 0, 0, resid);
    xin = xout;
  }
  // out = [h | h3] @ Wctr + bctr  (single K=256 GEMM, A2 = h3)
  hgemm_kernel<<<dim3(391, 2, 1), 256, 0, stream>>>(hb, 128, xin, WctrT2, 256, bctr, nullptr,
      (float*)d_out, 128, nullptr, 0, 0, NN, 0, 0, 0, 0, nullptr);
}

// Round 6
// 1061.969 us; speedup vs baseline: 1.4751x; 1.4751x over previous
//
#include <hip/hip_runtime.h>
#include <math.h>

#define NN 50000
#define NE 400000

typedef _Float16 f16;
typedef _Float16 f16x8 __attribute__((ext_vector_type(8)));
typedef _Float16 f16x4 __attribute__((ext_vector_type(4)));
typedef _Float16 f16x2 __attribute__((ext_vector_type(2)));
typedef float f32x4 __attribute__((ext_vector_type(4)));

static __device__ __forceinline__ float dot8(f16x8 a, f16x8 b, float acc) {
#if defined(__has_builtin) && __has_builtin(__builtin_amdgcn_fdot2)
#pragma unroll
  for (int j = 0; j < 4; ++j) {
    f16x2 x = {a[2 * j], a[2 * j + 1]};
    f16x2 y = {b[2 * j], b[2 * j + 1]};
    acc = __builtin_amdgcn_fdot2(x, y, acc, false);
  }
#else
#pragma unroll
  for (int j = 0; j < 8; ++j) acc += (float)a[j] * (float)b[j];
#endif
  return acc;
}

// ================= MFMA fp16 GEMM (proven rounds 3-5) =================
// A [M][lda] f16 (A2: optional second source for kc>=128), WT [Ntot][K] f16.
// fresid: fused epilogue -> outb = relu(acc + outf(read) + fresid), f16.
__global__ __launch_bounds__(256) void hgemm_kernel(
    const f16* __restrict__ A, int lda, const f16* __restrict__ A2,
    const f16* __restrict__ WT, int K,
    const float* __restrict__ bias,
    const float* __restrict__ rowscale,
    float* __restrict__ outf, int ldf,
    f16* __restrict__ outb, int ldb,
    int split_col, int M, int beta,
    const f16* __restrict__ fresid)
{
  __shared__ f16 As[128 * 128];
  __shared__ f16 Bs[64 * 128];
  const int t = threadIdx.x;
  const int wv = t >> 6, lane = t & 63;
  const int l15 = lane & 15, l4 = lane >> 4;
  const int row0 = blockIdx.x * 128;
  const int col0 = blockIdx.y * 64;

  f32x4 acc[2][4];
#pragma unroll
  for (int m = 0; m < 2; ++m)
#pragma unroll
    for (int n = 0; n < 4; ++n) acc[m][n] = (f32x4){0.f, 0.f, 0.f, 0.f};

  for (int kc = 0; kc < K; kc += 128) {
    const f16* Ap = (A2 && kc >= 128) ? A2 : A;
    const int koff = (A2 && kc >= 128) ? kc - 128 : kc;
    for (int i = t; i < 2048; i += 256) {
      int r = i >> 4, c8 = i & 15;
      int gr = row0 + r;
      float4 v = make_float4(0.f, 0.f, 0.f, 0.f);
      if (gr < M) v = *(const float4*)(Ap + (size_t)gr * lda + koff + c8 * 8);
      *(float4*)(As + r * 128 + ((c8 ^ (r & 15)) << 3)) = v;
    }
    for (int i = t; i < 1024; i += 256) {
      int c = i >> 4, c8 = i & 15;
      float4 v = *(const float4*)(WT + (size_t)(col0 + c) * K + kc + c8 * 8);
      *(float4*)(Bs + c * 128 + ((c8 ^ (c & 15)) << 3)) = v;
    }
    __syncthreads();
#pragma unroll
    for (int ks = 0; ks < 4; ++ks) {
      const int co = (((ks * 4 + l4) ^ l15) << 3);
      f16x8 a0 = *(const f16x8*)(As + (wv * 32 +      l15) * 128 + co);
      f16x8 a1 = *(const f16x8*)(As + (wv * 32 + 16 + l15) * 128 + co);
      f16x8 b0 = *(const f16x8*)(Bs + (     l15) * 128 + co);
      f16x8 b1 = *(const f16x8*)(Bs + (16 + l15) * 128 + co);
      f16x8 b2 = *(const f16x8*)(Bs + (32 + l15) * 128 + co);
      f16x8 b3 = *(const f16x8*)(Bs + (48 + l15) * 128 + co);
      acc[0][0] = __builtin_amdgcn_mfma_f32_16x16x32_f16(a0, b0, acc[0][0], 0, 0, 0);
      acc[0][1] = __builtin_amdgcn_mfma_f32_16x16x32_f16(a0, b1, acc[0][1], 0, 0, 0);
      acc[0][2] = __builtin_amdgcn_mfma_f32_16x16x32_f16(a0, b2, acc[0][2], 0, 0, 0);
      acc[0][3] = __builtin_amdgcn_mfma_f32_16x16x32_f16(a0, b3, acc[0][3], 0, 0, 0);
      acc[1][0] = __builtin_amdgcn_mfma_f32_16x16x32_f16(a1, b0, acc[1][0], 0, 0, 0);
      acc[1][1] = __builtin_amdgcn_mfma_f32_16x16x32_f16(a1, b1, acc[1][1], 0, 0, 0);
      acc[1][2] = __builtin_amdgcn_mfma_f32_16x16x32_f16(a1, b2, acc[1][2], 0, 0, 0);
      acc[1][3] = __builtin_amdgcn_mfma_f32_16x16x32_f16(a1, b3, acc[1][3], 0, 0, 0);
    }
    __syncthreads();
  }

  float bv4[4];
#pragma unroll
  for (int n = 0; n < 4; ++n) bv4[n] = bias ? bias[col0 + n * 16 + l15] : 0.f;
#pragma unroll
  for (int m = 0; m < 2; ++m) {
#pragma unroll
    for (int j = 0; j < 4; ++j) {
      int r = row0 + wv * 32 + m * 16 + l4 * 4 + j;
      if (r >= M) continue;
      float rsv = rowscale ? rowscale[r] : 1.f;
#pragma unroll
      for (int n = 0; n < 4; ++n) {
        int c = col0 + n * 16 + l15;
        float val = acc[m][n][j] * rsv + bv4[n];
        if (fresid) {
          val += outf[(size_t)r * ldf + c] + (float)fresid[(size_t)r * 128 + c];
          outb[(size_t)r * ldb + c] = (f16)fmaxf(val, 0.f);
        } else if (c < split_col) {
          outb[(size_t)r * ldb + c] = (f16)val;
        } else {
          float* p = outf + (size_t)r * ldf + (c - split_col);
          *p = (beta ? *p : 0.f) + val;
        }
      }
    }
  }
}

// ================= CSR build =================
__global__ void zero_int_kernel(int* __restrict__ p, int n) {
  int i = blockIdx.x * 256 + threadIdx.x;
  if (i < n) p[i] = 0;
}
__global__ void hist_kernel(const int* __restrict__ dst, int* __restrict__ deg) {
  int e = blockIdx.x * 256 + threadIdx.x;
  if (e < NE) atomicAdd(&deg[dst[e]], 1);
}
__global__ void scanA_kernel(const int* __restrict__ deg, int* __restrict__ rowstart,
                             int* __restrict__ part) {
  __shared__ int sd[256];
  int b = blockIdx.x, t = threadIdx.x, i = b * 256 + t;
  sd[t] = (i < NN) ? deg[i] : 0;
  __syncthreads();
  for (int o = 1; o < 256; o <<= 1) {
    int v = (t >= o) ? sd[t - o] : 0;
    __syncthreads();
    sd[t] += v;
    __syncthreads();
  }
  if (i < NN) rowstart[i + 1] = sd[t];
  if (t == 255) part[b] = sd[255];
}
__global__ void scanB_kernel(int* __restrict__ part, int nb) {
  __shared__ int sd[256];
  int t = threadIdx.x;
  sd[t] = (t < nb) ? part[t] : 0;
  __syncthreads();
  for (int o = 1; o < 256; o <<= 1) {
    int v = (t >= o) ? sd[t - o] : 0;
    __syncthreads();
    sd[t] += v;
    __syncthreads();
  }
  if (t < nb) part[t] = sd[t];
}
__global__ void scanC_kernel(const int* __restrict__ deg, int* __restrict__ rowstart,
                             const int* __restrict__ part, int* __restrict__ cursor) {
  int b = blockIdx.x, t = threadIdx.x, i = b * 256 + t;
  if (i >= NN) return;
  int off = b ? part[b - 1] : 0;
  int fin = rowstart[i + 1] + off;
  rowstart[i + 1] = fin;
  cursor[i] = fin - deg[i];
  if (i == 0) rowstart[0] = 0;
}
__global__ void scatter_kernel(const int* __restrict__ dst, const int* __restrict__ src,
                               const float* __restrict__ dirw, const float* __restrict__ geo,
                               int* __restrict__ cursor,
                               int* __restrict__ srcp, f16* __restrict__ dirpb,
                               f16* __restrict__ geop) {
  int e = blockIdx.x * 256 + threadIdx.x;
  if (e < NE) {
    int pos = atomicAdd(&cursor[dst[e]], 1);
    srcp[pos] = src[e];
    float dv = dirw[e];
    dirpb[pos] = (f16)dv;
    f16* gp = geop + (size_t)pos * 24;
#pragma unroll
    for (int j = 0; j < 20; ++j) gp[j] = (f16)geo[(size_t)e * 20 + j];
    gp[20] = (f16)dv;
    gp[21] = (f16)0.f; gp[22] = (f16)0.f; gp[23] = (f16)0.f;
  }
}
__global__ void swc_kernel(const int* __restrict__ deg, float* __restrict__ swc) {
  int n = blockIdx.x * 256 + threadIdx.x;
  if (n < NN) swc[n] = deg[n] ? 1.0f : 0.0f;
}

// ================= stage-1 weight prep (proven round 2+) =================
// mats[layer] floats: M2T[3][128c][128u] @0; M34T[3][128c][24t] @49152; WW2[3][128t][128c] @58368;
//                     WWg[3][21][128] @107520; bvec[3][128] @115584; Wsum0[128k][128c] @115968
__global__ void prep_kernel(const float* __restrict__ Wee, const float* __restrict__ bee,
                            const float* __restrict__ WeAll, const float* __restrict__ beAll,
                            float* __restrict__ matsAll)
{
  const int layer = blockIdx.y;
  const float* We = WeAll + (size_t)layer * 49152;
  const float* be = beAll + (size_t)layer * 384;
  float* mats = matsAll + (size_t)layer * 132352;
  int idx = blockIdx.x * 256 + threadIdx.x;
  if (idx >= 132352) return;
  float acc = 0.0f;
  if (idx < 49152) {
    int h = idx >> 14, rem = idx & 16383, c = rem >> 7, u = rem & 127;
    for (int j = 0; j < 128; ++j)
      acc += We[(size_t)j * 384 + h * 128 + c] * Wee[(size_t)(128 + u) * 128 + j];
    mats[idx] = acc;
  } else if (idx < 58368) {
    int r = idx - 49152; int h = r / 3072; int rem = r - h * 3072; int c = rem / 24; int u = rem - c * 24;
    if (u < 21) {
      int trow = (u < 20) ? (257 + u) : 256;
      for (int j = 0; j < 128; ++j)
        acc += We[(size_t)j * 384 + h * 128 + c] * Wee[(size_t)trow * 128 + j];
    }
    mats[idx] = acc;
  } else if (idx < 107520) {
    int r = idx - 58368; int h = r >> 14; int rem = r & 16383; int tt = rem >> 7; int c = rem & 127;
    for (int j = 0; j < 128; ++j)
      acc += Wee[(size_t)(128 + tt) * 128 + j] * We[(size_t)j * 384 + h * 128 + c];
    mats[idx] = acc;
  } else if (idx < 115584) {
    int r = idx - 107520; int h = r / 2688; int rem = r - h * 2688; int tt = rem >> 7; int c = rem & 127;
    int trow = (tt < 20) ? (257 + tt) : 256;
    for (int j = 0; j < 128; ++j)
      acc += Wee[(size_t)trow * 128 + j] * We[(size_t)j * 384 + h * 128 + c];
    mats[idx] = acc;
  } else if (idx < 115968) {
    int r = idx - 115584; int h = r >> 7; int c = r & 127;
    for (int j = 0; j < 128; ++j)
      acc += bee[j] * We[(size_t)j * 384 + h * 128 + c];
    mats[idx] = acc + be[h * 128 + c];
  } else {
    int r = idx - 115968; int tt = r >> 7; int c = r & 127;
    for (int j = 0; j < 128; ++j)
      acc += Wee[(size_t)tt * 128 + j] *
             (We[(size_t)j * 384 + c] + We[(size_t)j * 384 + 128 + c] + We[(size_t)j * 384 + 256 + c]);
    mats[idx] = acc * (1.0f / 3.0f);
  }
}

// ================= stage-2a: fat-GEMM weights WABT[3l][1024c][128k] + biasAB[3l][1024] =================
// cols: 0..383 qk (A_h = Wq_h@Wk_h^T); 384..767 g2 (B_h = Wq_h@M2T_h); 768..839 g34 (C34_h);
//       840..895 zero; 896..1023 skip (Ws).  bq pushed through the same mats -> biases.
__global__ void prepB_kernel(const float* __restrict__ Wq, const float* __restrict__ bq,
                             const float* __restrict__ Wk, const float* __restrict__ Ws,
                             const float* __restrict__ bs, const float* __restrict__ matsAll,
                             f16* __restrict__ WABT, float* __restrict__ biasAB)
{
  int idx = blockIdx.x * 256 + threadIdx.x;
  if (idx < 393216) {                       // weights
    int i = idx >> 17; int r = idx & 131071; int c = r >> 7; int k = r & 127;
    float acc = 0.f;
    if (c < 384) {
      int h = c >> 7, u = c & 127;
      const float* wq = Wq + ((size_t)i * 128 + k) * 384 + h * 128;
      const float* wk = Wk + ((size_t)i * 128 + u) * 384 + h * 128;
      for (int c2 = 0; c2 < 128; ++c2) acc += wq[c2] * wk[c2];
    } else if (c < 768) {
      int h = (c - 384) >> 7, u = (c - 384) & 127;
      const float* wq = Wq + ((size_t)i * 128 + k) * 384 + h * 128;
      const float* m2 = matsAll + (size_t)i * 132352 + h * 16384 + u;
      for (int c2 = 0; c2 < 128; ++c2) acc += wq[c2] * m2[c2 * 128];
    } else if (c < 840) {
      int h = (c - 768) / 24, t = (c - 768) % 24;
      const float* wq = Wq + ((size_t)i * 128 + k) * 384 + h * 128;
      const float* m34 = matsAll + (size_t)i * 132352 + 49152 + h * 3072 + t;
      for (int c2 = 0; c2 < 128; ++c2) acc += wq[c2] * m34[c2 * 24];
    } else if (c < 896) {
      acc = 0.f;
    } else {
      acc = Ws[((size_t)i * 128 + k) * 128 + (c - 896)];
    }
    WABT[(size_t)i * 131072 + c * 128 + k] = (f16)acc;
  } else if (idx < 396288) {                // biases
    int r = idx - 393216; int i = r / 1024; int c = r % 1024;
    float acc = 0.f;
    if (c < 384) {
      int h = c >> 7, u = c & 127;
      const float* bqv = bq + i * 384 + h * 128;
      const float* wk = Wk + ((size_t)i * 128 + u) * 384 + h * 128;
      for (int c2 = 0; c2 < 128; ++c2) acc += bqv[c2] * wk[c2];
    } else if (c < 768) {
      int h = (c - 384) >> 7, u = (c - 384) & 127;
      const float* bqv = bq + i * 384 + h * 128;
      const float* m2 = matsAll + (size_t)i * 132352 + h * 16384 + u;
      for (int c2 = 0; c2 < 128; ++c2) acc += bqv[c2] * m2[c2 * 128];
    } else if (c < 840) {
      int h = (c - 768) / 24, t = (c - 768) % 24;
      const float* bqv = bq + i * 384 + h * 128;
      const float* m34 = matsAll + (size_t)i * 132352 + 49152 + h * 3072 + t;
      for (int c2 = 0; c2 < 128; ++c2) acc += bqv[c2] * m34[c2 * 24];
    } else if (c < 896) {
      acc = 0.f;
    } else {
      acc = bs[i * 128 + (c - 896)];
    }
    biasAB[i * 1024 + c] = acc;
  }
}

// ================= stage-2b: output-GEMM weights W2bigT[3l][128c][896k] + Ws0T =================
// k rows: 0..383 WW2 (F2 path); 384..767 Wv (Fv path); 768..839 WWg/bvec+bv (fg path); rest 0.
__global__ void prep2_kernel(const float* __restrict__ matsAll, const float* __restrict__ Wv,
                             const float* __restrict__ bv,
                             f16* __restrict__ W2bigT, f16* __restrict__ Ws0T)
{
  int idx = blockIdx.x * 256 + threadIdx.x;
  if (idx < 344064) {
    int i = idx / 114688; int r = idx % 114688; int c = r / 896; int k = r % 896;
    float v = 0.f;
    if (k < 384) {
      int h = k >> 7, t = k & 127;
      v = matsAll[(size_t)i * 132352 + 58368 + h * 16384 + t * 128 + c];
    } else if (k < 768) {
      int h = (k - 384) >> 7, u = (k - 384) & 127;
      v = Wv[((size_t)i * 128 + u) * 384 + h * 128 + c];
    } else if (k < 840) {
      int h = (k - 768) / 24, t = (k - 768) % 24;
      if (t < 21)       v = matsAll[(size_t)i * 132352 + 107520 + h * 2688 + t * 128 + c];
      else if (t == 21) v = matsAll[(size_t)i * 132352 + 115584 + h * 128 + c]
                          + bv[i * 384 + h * 128 + c];
    }
    W2bigT[(size_t)i * 114688 + c * 896 + k] = (f16)v;
  } else if (idx < 393216) {
    int r = idx - 344064; int i = r / 16384; int rr = r % 16384; int c = rr >> 7; int k = rr & 127;
    Ws0T[i * 16384 + rr] = (f16)matsAll[(size_t)i * 132352 + 115968 + k * 128 + c];
  }
}

// small weights: WresT [128c][128k], WctrT2 [128c][256k]
__global__ void wprep_kernel(const float* __restrict__ Wres, const float* __restrict__ Wctr,
                             f16* __restrict__ WresT, f16* __restrict__ WctrT2)
{
  int idx = blockIdx.x * 256 + threadIdx.x;
  if (idx < 16384) {
    int c = idx >> 7, k = idx & 127;
    WresT[idx] = (f16)Wres[k * 128 + c];
  } else if (idx < 49152) {
    int r = idx - 16384; int c = r >> 8, k = r & 255;
    WctrT2[r] = (f16)Wctr[(size_t)k * 128 + c];
  }
}

// ================= attention v4: node-side qk/g2/g34, per-edge gather = x[src],h[src] only ====
// nb [N,896]: in cols 0..383 qk | 384..767 g2 | 768..839 g34 (self-aliased out: F2|Fv|fg)
__global__ __launch_bounds__(256) void attn_kernel(
    const f16* __restrict__ xb,     // current layer x [N,128] f16
    const f16* __restrict__ hb,     // original h [N,128] f16
    f16* __restrict__ nb,
    const int* __restrict__ rowstart,
    const int* __restrict__ srcp,
    const f16* __restrict__ dirpb,
    const f16* __restrict__ geop)
{
  const int sl = threadIdx.x & 15;
  const int n = blockIdx.x * 16 + (threadIdx.x >> 4);
  const float rsC = 0.088388347648318447f;  // 1/sqrt(128)
  f16* row = nb + (size_t)n * 896;

  f16x8 qk[3], g2[3];
#pragma unroll
  for (int h = 0; h < 3; ++h) {
    qk[h] = *(const f16x8*)(row + h * 128 + sl * 8);
    g2[h] = *(const f16x8*)(row + 384 + h * 128 + sl * 8);
  }
  float g34a[3], g34c[3];
#pragma unroll
  for (int h = 0; h < 3; ++h) {
    g34a[h] = (float)row[768 + h * 24 + sl];
    g34c[h] = (sl < 8) ? (float)row[768 + h * 24 + 16 + sl] : 0.f;
  }
  float den0 = 0.f, den1 = 0.f, den2 = 0.f;
  float F2[3][8], Fv[3][8];
#pragma unroll
  for (int h = 0; h < 3; ++h)
#pragma unroll
    for (int j = 0; j < 8; ++j) { F2[h][j] = 0.f; Fv[h][j] = 0.f; }
  float f34a[3] = {0.f, 0.f, 0.f}, f34c[3] = {0.f, 0.f, 0.f};

  const int beg = rowstart[n], end = rowstart[n + 1];
  for (int ii = beg; ii < end; ++ii) {
    const int s = srcp[ii];
    const float d = (float)dirpb[ii];
    f16x8 xv = *(const f16x8*)(xb + (size_t)s * 128 + sl * 8);
    f16x8 hv = *(const f16x8*)(hb + (size_t)s * 128 + sl * 8);
    const float gea = (float)geop[(size_t)ii * 24 + sl];
    const float geb = (sl < 8) ? (float)geop[(size_t)ii * 24 + 16 + sl] : 0.f;

    float pa0 = dot8(qk[0], xv, 0.f) + d * dot8(g2[0], hv, 0.f) + gea * g34a[0] + geb * g34c[0];
    float pa1 = dot8(qk[1], xv, 0.f) + d * dot8(g2[1], hv, 0.f) + gea * g34a[1] + geb * g34c[1];
    float pa2 = dot8(qk[2], xv, 0.f) + d * dot8(g2[2], hv, 0.f) + gea * g34a[2] + geb * g34c[2];
#pragma unroll
    for (int off = 1; off < 16; off <<= 1) {
      pa0 += __shfl_xor(pa0, off);
      pa1 += __shfl_xor(pa1, off);
      pa2 += __shfl_xor(pa2, off);
    }
    const float w0 = __expf(pa0 * rsC);
    const float w1 = __expf(pa1 * rsC);
    const float w2 = __expf(pa2 * rsC);
    den0 += w0; den1 += w1; den2 += w2;
    const float wd0 = w0 * d, wd1 = w1 * d, wd2 = w2 * d;
#pragma unroll
    for (int j = 0; j < 8; ++j) {
      const float hf = (float)hv[j];
      const float xf = (float)xv[j];
      F2[0][j] = fmaf(wd0, hf, F2[0][j]);
      F2[1][j] = fmaf(wd1, hf, F2[1][j]);
      F2[2][j] = fmaf(wd2, hf, F2[2][j]);
      Fv[0][j] = fmaf(w0, xf, Fv[0][j]);
      Fv[1][j] = fmaf(w1, xf, Fv[1][j]);
      Fv[2][j] = fmaf(w2, xf, Fv[2][j]);
    }
    f34a[0] = fmaf(w0, gea, f34a[0]); f34a[1] = fmaf(w1, gea, f34a[1]); f34a[2] = fmaf(w2, gea, f34a[2]);
    f34c[0] = fmaf(w0, geb, f34c[0]); f34c[1] = fmaf(w1, geb, f34c[1]); f34c[2] = fmaf(w2, geb, f34c[2]);
  }

  float sc[3], swh[3], dens[3] = {den0, den1, den2};
#pragma unroll
  for (int h = 0; h < 3; ++h) {
    sc[h] = (1.f / 3.f) / (dens[h] + 1e-16f);
    swh[h] = dens[h] * sc[h];
  }
#pragma unroll
  for (int h = 0; h < 3; ++h) {
    f16x8 o1, o2;
#pragma unroll
    for (int j = 0; j < 8; ++j) {
      o1[j] = (f16)(F2[h][j] * sc[h]);
      o2[j] = (f16)(Fv[h][j] * sc[h]);
    }
    *(f16x8*)(row + h * 128 + sl * 8) = o1;
    *(f16x8*)(row + 384 + h * 128 + sl * 8) = o2;
  }
#pragma unroll
  for (int h = 0; h < 3; ++h) {
    row[768 + h * 24 + sl] = (f16)(f34a[h] * sc[h]);
    if (sl < 8) {
      float fcv = (sl == 5) ? swh[h] : f34c[h] * sc[h];
      row[768 + h * 24 + 16 + sl] = (f16)fcv;
    }
  }
}

// ================= h f32 -> f16 =================
__global__ void hconv_kernel(const float* __restrict__ src, f16* __restrict__ hb) {
  int i = blockIdx.x * 256 + threadIdx.x;
  if (i >= NN * 32) return;
  float4 a = ((const float4*)src)[i];
  f16x4 o;
  o[0] = (f16)a.x; o[1] = (f16)a.y; o[2] = (f16)a.z; o[3] = (f16)a.w;
  ((f16x4*)hb)[i] = o;
}

// ================= launch =================
extern "C" void kernel_launch(void* const* d_in, const int* in_sizes, int n_in,
                              void* d_out, int out_size, void* d_ws, size_t ws_size,
                              hipStream_t stream)
{
  (void)in_sizes; (void)n_in; (void)out_size; (void)ws_size;
  const float* h    = (const float*)d_in[0];
  const float* geo  = (const float*)d_in[1];
  const float* dirw = (const float*)d_in[2];
  const int*   src  = (const int*)d_in[3];
  const int*   dst  = (const int*)d_in[4];
  const float* Wee  = (const float*)d_in[5];
  const float* bee  = (const float*)d_in[6];
  const float* Wres = (const float*)d_in[7];
  const float* bres = (const float*)d_in[8];
  const float* Wq   = (const float*)d_in[9];
  const float* bq   = (const float*)d_in[10];
  const float* Wk   = (const float*)d_in[11];
  const float* bk   = (const float*)d_in[12];  (void)bk;  // cancels in softmax
  const float* Wv   = (const float*)d_in[13];
  const float* bv   = (const float*)d_in[14];
  const float* We   = (const float*)d_in[15];
  const float* be   = (const float*)d_in[16];
  const float* Ws   = (const float*)d_in[17];
  const float* bs   = (const float*)d_in[18];
  const float* Wctr = (const float*)d_in[19];
  const float* bctr = (const float*)d_in[20];
  float* tmp1 = (float*)d_out;     // d_out doubles as per-layer fp32 accumulator

  char* base = (char*)d_ws;
  size_t off = 0;
  auto take = [&](size_t bytes) -> char* {
    char* p = base + off;
    off += bytes;
    off = (off + 255) & ~(size_t)255;
    return p;
  };
  f16* nbuf     = (f16*)take((size_t)NN * 896 * 2);     // qk|g2|g34 -> F2|Fv|fg
  f16* hb       = (f16*)take((size_t)NN * 128 * 2);
  f16* xb1      = (f16*)take((size_t)NN * 128 * 2);
  f16* xb2      = (f16*)take((size_t)NN * 128 * 2);
  float* mats   = (float*)take((size_t)3 * 132352 * 4);
  f16* WABT     = (f16*)take((size_t)3 * 131072 * 2);
  float* biasAB = (float*)take((size_t)3 * 1024 * 4);
  f16* W2bigT   = (f16*)take((size_t)3 * 114688 * 2);
  f16* Ws0T     = (f16*)take((size_t)3 * 16384 * 2);
  f16* WresT    = (f16*)take(16384 * 2);
  f16* WctrT2   = (f16*)take(32768 * 2);
  float* swc    = (float*)take((size_t)NN * 4);
  f16* dirpb    = (f16*)take((size_t)NE * 2);
  f16* geop     = (f16*)take((size_t)NE * 24 * 2);
  int* deg      = (int*)take((size_t)NN * 4);
  int* rowstart = (int*)take((size_t)(NN + 1) * 4);
  int* cursor   = (int*)take((size_t)NN * 4);
  int* srcp     = (int*)take((size_t)NE * 4);
  int* part     = (int*)take(256 * 4);

  // CSR by dst
  zero_int_kernel<<<(NN + 255) / 256, 256, 0, stream>>>(deg, NN);
  hist_kernel<<<(NE + 255) / 256, 256, 0, stream>>>(dst, deg);
  scanA_kernel<<<196, 256, 0, stream>>>(deg, rowstart, part);
  scanB_kernel<<<1, 256, 0, stream>>>(part, 196);
  scanC_kernel<<<196, 256, 0, stream>>>(deg, rowstart, part, cursor);
  scatter_kernel<<<(NE + 255) / 256, 256, 0, stream>>>(dst, src, dirw, geo, cursor,
                                                       srcp, dirpb, geop);
  swc_kernel<<<(NN + 255) / 256, 256, 0, stream>>>(deg, swc);
  hconv_kernel<<<6250, 256, 0, stream>>>(h, hb);
  wprep_kernel<<<192, 256, 0, stream>>>(Wres, Wctr, WresT, WctrT2);
  prep_kernel<<<dim3(518, 3), 256, 0, stream>>>(Wee, bee, We, be, mats);
  prepB_kernel<<<(396288 + 255) / 256, 256, 0, stream>>>(Wq, bq, Wk, Ws, bs, mats, WABT, biasAB);
  prep2_kernel<<<(393216 + 255) / 256, 256, 0, stream>>>(mats, Wv, bv, W2bigT, Ws0T);

  // layer-0 residual (f16) -> xb2
  hgemm_kernel<<<dim3(391, 2, 1), 256, 0, stream>>>(hb, 128, nullptr, WresT, 128, bres, nullptr,
      nullptr, 0, xb2, 128, 1 << 30, NN, 0, nullptr);

  const f16* xin = hb;
  for (int i = 0; i < 3; ++i) {
    // fat: x @ [A|B|C34|pad|Ws] -> nb cols 0..895 (f16), skip -> tmp1 (f32, fresh)
    hgemm_kernel<<<dim3(391, 16, 1), 256, 0, stream>>>(xin, 128, nullptr,
        WABT + (size_t)i * 131072, 128, biasAB + (size_t)i * 1024, nullptr,
        tmp1, 128, nbuf, 896, 896, NN, 0, nullptr);
    // tmp1 += mask * (h @ Wsum0)
    hgemm_kernel<<<dim3(391, 2, 1), 256, 0, stream>>>(hb, 128, nullptr,
        Ws0T + (size_t)i * 16384, 128, nullptr, swc, tmp1, 128,
        nullptr, 0, 0, NN, 1, nullptr);
    // attention (reads+rewrites its own nb row)
    attn_kernel<<<3125, 256, 0, stream>>>(xin, hb, nbuf, rowstart, srcp, dirpb, geop);
    // fused: xout = relu([F2|Fv|fg] @ W2big + tmp1 + resid), f16
    const f16* resid = (i == 0) ? xb2 : xin;
    f16* xout = (i == 1) ? xb2 : xb1;
    hgemm_kernel<<<dim3(391, 2, 1), 256, 0, stream>>>(nbuf, 896, nullptr,
        W2bigT + (size_t)i * 114688, 896, nullptr, nullptr, tmp1, 128,
        xout, 128, 0, NN, 0, resid);
    xin = xout;
  }
  // out = [h | h3] @ Wctr + bctr  (single K=256 GEMM, A2 = h3)
  hgemm_kernel<<<dim3(391, 2, 1), 256, 0, stream>>>(hb, 128, xin, WctrT2, 256, bctr, nullptr,
      (float*)d_out, 128, nullptr, 0, 0, NN, 0, nullptr);
}

// Round 7
// 773.810 us; speedup vs baseline: 2.0244x; 1.3724x over previous
//
#include <hip/hip_runtime.h>
#include <math.h>

#define NN 50000
#define NE 400000

typedef _Float16 f16;
typedef _Float16 f16x8 __attribute__((ext_vector_type(8)));
typedef _Float16 f16x4 __attribute__((ext_vector_type(4)));
typedef _Float16 f16x2 __attribute__((ext_vector_type(2)));
typedef float f32x4 __attribute__((ext_vector_type(4)));

static __device__ __forceinline__ float dot8(f16x8 a, f16x8 b, float acc) {
#if defined(__has_builtin) && __has_builtin(__builtin_amdgcn_fdot2)
#pragma unroll
  for (int j = 0; j < 4; ++j) {
    f16x2 x = {a[2 * j], a[2 * j + 1]};
    f16x2 y = {b[2 * j], b[2 * j + 1]};
    acc = __builtin_amdgcn_fdot2(x, y, acc, false);
  }
#else
#pragma unroll
  for (int j = 0; j < 8; ++j) acc += (float)a[j] * (float)b[j];
#endif
  return acc;
}

// ========== hgemm_k128: K=128, A staged ONCE, col-tile loop (fat/resid GEMMs) ==========
// A [M][lda] f16; WT [ncols][128]; out f16 [M][ldb]. grid=(ceil(M/128), ygroups); block 256.
// Each block covers ntiles consecutive 64-col tiles starting at blockIdx.y*ntiles*64.
__global__ __launch_bounds__(256) void hgemm_k128_kernel(
    const f16* __restrict__ A, int lda,
    const f16* __restrict__ WT,
    const float* __restrict__ bias,
    f16* __restrict__ outb, int ldb,
    int M, int ntiles)
{
  __shared__ f16 As[128 * 128];
  __shared__ f16 Bs[64 * 128];
  const int t = threadIdx.x;
  const int wv = t >> 6, lane = t & 63;
  const int l15 = lane & 15, l4 = lane >> 4;
  const int row0 = blockIdx.x * 128;

  for (int i = t; i < 2048; i += 256) {           // stage A once
    int r = i >> 4, c8 = i & 15;
    int gr = row0 + r;
    float4 v = make_float4(0.f, 0.f, 0.f, 0.f);
    if (gr < M) v = *(const float4*)(A + (size_t)gr * lda + c8 * 8);
    *(float4*)(As + r * 128 + ((c8 ^ (r & 15)) << 3)) = v;
  }
  for (int ct = 0; ct < ntiles; ++ct) {
    const int col0 = (blockIdx.y * ntiles + ct) * 64;
    for (int i = t; i < 1024; i += 256) {
      int c = i >> 4, c8 = i & 15;
      float4 v = *(const float4*)(WT + (size_t)(col0 + c) * 128 + c8 * 8);
      *(float4*)(Bs + c * 128 + ((c8 ^ (c & 15)) << 3)) = v;
    }
    __syncthreads();
    f32x4 acc[2][4];
#pragma unroll
    for (int m = 0; m < 2; ++m)
#pragma unroll
      for (int n = 0; n < 4; ++n) acc[m][n] = (f32x4){0.f, 0.f, 0.f, 0.f};
#pragma unroll
    for (int ks = 0; ks < 4; ++ks) {
      const int co = (((ks * 4 + l4) ^ l15) << 3);
      f16x8 a0 = *(const f16x8*)(As + (wv * 32 +      l15) * 128 + co);
      f16x8 a1 = *(const f16x8*)(As + (wv * 32 + 16 + l15) * 128 + co);
      f16x8 b0 = *(const f16x8*)(Bs + (     l15) * 128 + co);
      f16x8 b1 = *(const f16x8*)(Bs + (16 + l15) * 128 + co);
      f16x8 b2 = *(const f16x8*)(Bs + (32 + l15) * 128 + co);
      f16x8 b3 = *(const f16x8*)(Bs + (48 + l15) * 128 + co);
      acc[0][0] = __builtin_amdgcn_mfma_f32_16x16x32_f16(a0, b0, acc[0][0], 0, 0, 0);
      acc[0][1] = __builtin_amdgcn_mfma_f32_16x16x32_f16(a0, b1, acc[0][1], 0, 0, 0);
      acc[0][2] = __builtin_amdgcn_mfma_f32_16x16x32_f16(a0, b2, acc[0][2], 0, 0, 0);
      acc[0][3] = __builtin_amdgcn_mfma_f32_16x16x32_f16(a0, b3, acc[0][3], 0, 0, 0);
      acc[1][0] = __builtin_amdgcn_mfma_f32_16x16x32_f16(a1, b0, acc[1][0], 0, 0, 0);
      acc[1][1] = __builtin_amdgcn_mfma_f32_16x16x32_f16(a1, b1, acc[1][1], 0, 0, 0);
      acc[1][2] = __builtin_amdgcn_mfma_f32_16x16x32_f16(a1, b2, acc[1][2], 0, 0, 0);
      acc[1][3] = __builtin_amdgcn_mfma_f32_16x16x32_f16(a1, b3, acc[1][3], 0, 0, 0);
    }
    __syncthreads();
    float bv4[4];
#pragma unroll
    for (int n = 0; n < 4; ++n) bv4[n] = bias ? bias[col0 + n * 16 + l15] : 0.f;
#pragma unroll
    for (int m = 0; m < 2; ++m) {
#pragma unroll
      for (int j = 0; j < 4; ++j) {
        int r = row0 + wv * 32 + m * 16 + l4 * 4 + j;
        if (r >= M) continue;
#pragma unroll
        for (int n = 0; n < 4; ++n) {
          int c = col0 + n * 16 + l15;
          outb[(size_t)r * ldb + c] = (f16)(acc[m][n][j] + bv4[n]);
        }
      }
    }
  }
}

// ========== hgemm2: general-K, 128-wide col tile, dual A source, fused relu+resid ==========
// A [M][lda] for kc < a2k; A2 [M][lda2] for kc >= a2k (koff = kc - a2k). WT [128c][K].
// fresid != null: outb = relu(acc + bias + fresid). outb==null -> outf f32 (no relu).
__global__ __launch_bounds__(256) void hgemm2_kernel(
    const f16* __restrict__ A, int lda,
    const f16* __restrict__ A2, int lda2, int a2k,
    const f16* __restrict__ WT, int K,
    const float* __restrict__ bias,
    float* __restrict__ outf,
    f16* __restrict__ outb, int ldb,
    const f16* __restrict__ fresid, int ldr,
    int M)
{
  __shared__ f16 As[128 * 128];
  __shared__ f16 Bs[128 * 128];
  const int t = threadIdx.x;
  const int wv = t >> 6, lane = t & 63;
  const int l15 = lane & 15, l4 = lane >> 4;
  const int row0 = blockIdx.x * 128;
  const int col0 = blockIdx.y * 128;

  f32x4 acc[2][8];
#pragma unroll
  for (int m = 0; m < 2; ++m)
#pragma unroll
    for (int n = 0; n < 8; ++n) acc[m][n] = (f32x4){0.f, 0.f, 0.f, 0.f};

  for (int kc = 0; kc < K; kc += 128) {
    const f16* Ap; int koff, ldA;
    if (kc >= a2k) { Ap = A2; koff = kc - a2k; ldA = lda2; }
    else           { Ap = A;  koff = kc;       ldA = lda;  }
    for (int i = t; i < 2048; i += 256) {
      int r = i >> 4, c8 = i & 15;
      int gr = row0 + r;
      float4 v = make_float4(0.f, 0.f, 0.f, 0.f);
      if (gr < M) v = *(const float4*)(Ap + (size_t)gr * ldA + koff + c8 * 8);
      *(float4*)(As + r * 128 + ((c8 ^ (r & 15)) << 3)) = v;
    }
    for (int i = t; i < 2048; i += 256) {
      int c = i >> 4, c8 = i & 15;
      float4 v = *(const float4*)(WT + (size_t)(col0 + c) * K + kc + c8 * 8);
      *(float4*)(Bs + c * 128 + ((c8 ^ (c & 15)) << 3)) = v;
    }
    __syncthreads();
#pragma unroll
    for (int ks = 0; ks < 4; ++ks) {
      const int co = (((ks * 4 + l4) ^ l15) << 3);
      f16x8 a0 = *(const f16x8*)(As + (wv * 32 +      l15) * 128 + co);
      f16x8 a1 = *(const f16x8*)(As + (wv * 32 + 16 + l15) * 128 + co);
#pragma unroll
      for (int n = 0; n < 8; ++n) {
        f16x8 b = *(const f16x8*)(Bs + (n * 16 + l15) * 128 + co);
        acc[0][n] = __builtin_amdgcn_mfma_f32_16x16x32_f16(a0, b, acc[0][n], 0, 0, 0);
        acc[1][n] = __builtin_amdgcn_mfma_f32_16x16x32_f16(a1, b, acc[1][n], 0, 0, 0);
      }
    }
    __syncthreads();
  }

  float bv8[8];
#pragma unroll
  for (int n = 0; n < 8; ++n) bv8[n] = bias ? bias[col0 + n * 16 + l15] : 0.f;
#pragma unroll
  for (int m = 0; m < 2; ++m) {
#pragma unroll
    for (int j = 0; j < 4; ++j) {
      int r = row0 + wv * 32 + m * 16 + l4 * 4 + j;
      if (r >= M) continue;
#pragma unroll
      for (int n = 0; n < 8; ++n) {
        int c = col0 + n * 16 + l15;
        float val = acc[m][n][j] + bv8[n];
        if (fresid) {
          val += (float)fresid[(size_t)r * ldr + c];
          val = fmaxf(val, 0.f);
        }
        if (outb) outb[(size_t)r * ldb + c] = (f16)val;
        else      outf[(size_t)r * 128 + c] = val;
      }
    }
  }
}

// ================= CSR build =================
__global__ void zero_int_kernel(int* __restrict__ p, int n) {
  int i = blockIdx.x * 256 + threadIdx.x;
  if (i < n) p[i] = 0;
}
__global__ void hist_kernel(const int* __restrict__ dst, int* __restrict__ deg) {
  int e = blockIdx.x * 256 + threadIdx.x;
  if (e < NE) atomicAdd(&deg[dst[e]], 1);
}
__global__ void scanA_kernel(const int* __restrict__ deg, int* __restrict__ rowstart,
                             int* __restrict__ part) {
  __shared__ int sd[256];
  int b = blockIdx.x, t = threadIdx.x, i = b * 256 + t;
  sd[t] = (i < NN) ? deg[i] : 0;
  __syncthreads();
  for (int o = 1; o < 256; o <<= 1) {
    int v = (t >= o) ? sd[t - o] : 0;
    __syncthreads();
    sd[t] += v;
    __syncthreads();
  }
  if (i < NN) rowstart[i + 1] = sd[t];
  if (t == 255) part[b] = sd[255];
}
__global__ void scanB_kernel(int* __restrict__ part, int nb) {
  __shared__ int sd[256];
  int t = threadIdx.x;
  sd[t] = (t < nb) ? part[t] : 0;
  __syncthreads();
  for (int o = 1; o < 256; o <<= 1) {
    int v = (t >= o) ? sd[t - o] : 0;
    __syncthreads();
    sd[t] += v;
    __syncthreads();
  }
  if (t < nb) part[t] = sd[t];
}
__global__ void scanC_kernel(const int* __restrict__ deg, int* __restrict__ rowstart,
                             const int* __restrict__ part, int* __restrict__ cursor) {
  int b = blockIdx.x, t = threadIdx.x, i = b * 256 + t;
  if (i >= NN) return;
  int off = b ? part[b - 1] : 0;
  int fin = rowstart[i + 1] + off;
  rowstart[i + 1] = fin;
  cursor[i] = fin - deg[i];
  if (i == 0) rowstart[0] = 0;
}
__global__ void scatter_kernel(const int* __restrict__ dst, const int* __restrict__ src,
                               const float* __restrict__ dirw, const float* __restrict__ geo,
                               int* __restrict__ cursor,
                               int* __restrict__ srcp, f16* __restrict__ dirpb,
                               f16* __restrict__ geop) {
  int e = blockIdx.x * 256 + threadIdx.x;
  if (e < NE) {
    int pos = atomicAdd(&cursor[dst[e]], 1);
    srcp[pos] = src[e];
    float dv = dirw[e];
    dirpb[pos] = (f16)dv;
    f16* gp = geop + (size_t)pos * 24;
#pragma unroll
    for (int j = 0; j < 20; ++j) gp[j] = (f16)geo[(size_t)e * 20 + j];
    gp[20] = (f16)dv;
    gp[21] = (f16)0.f; gp[22] = (f16)0.f; gp[23] = (f16)0.f;
  }
}

// ================= stage-1 weight prep (proven) =================
__global__ void prep_kernel(const float* __restrict__ Wee, const float* __restrict__ bee,
                            const float* __restrict__ WeAll, const float* __restrict__ beAll,
                            float* __restrict__ matsAll)
{
  const int layer = blockIdx.y;
  const float* We = WeAll + (size_t)layer * 49152;
  const float* be = beAll + (size_t)layer * 384;
  float* mats = matsAll + (size_t)layer * 132352;
  int idx = blockIdx.x * 256 + threadIdx.x;
  if (idx >= 132352) return;
  float acc = 0.0f;
  if (idx < 49152) {
    int h = idx >> 14, rem = idx & 16383, c = rem >> 7, u = rem & 127;
    for (int j = 0; j < 128; ++j)
      acc += We[(size_t)j * 384 + h * 128 + c] * Wee[(size_t)(128 + u) * 128 + j];
    mats[idx] = acc;
  } else if (idx < 58368) {
    int r = idx - 49152; int h = r / 3072; int rem = r - h * 3072; int c = rem / 24; int u = rem - c * 24;
    if (u < 21) {
      int trow = (u < 20) ? (257 + u) : 256;
      for (int j = 0; j < 128; ++j)
        acc += We[(size_t)j * 384 + h * 128 + c] * Wee[(size_t)trow * 128 + j];
    }
    mats[idx] = acc;
  } else if (idx < 107520) {
    int r = idx - 58368; int h = r >> 14; int rem = r & 16383; int tt = rem >> 7; int c = rem & 127;
    for (int j = 0; j < 128; ++j)
      acc += Wee[(size_t)(128 + tt) * 128 + j] * We[(size_t)j * 384 + h * 128 + c];
    mats[idx] = acc;
  } else if (idx < 115584) {
    int r = idx - 107520; int h = r / 2688; int rem = r - h * 2688; int tt = rem >> 7; int c = rem & 127;
    int trow = (tt < 20) ? (257 + tt) : 256;
    for (int j = 0; j < 128; ++j)
      acc += Wee[(size_t)trow * 128 + j] * We[(size_t)j * 384 + h * 128 + c];
    mats[idx] = acc;
  } else if (idx < 115968) {
    int r = idx - 115584; int h = r >> 7; int c = r & 127;
    for (int j = 0; j < 128; ++j)
      acc += bee[j] * We[(size_t)j * 384 + h * 128 + c];
    mats[idx] = acc + be[h * 128 + c];
  } else {
    int r = idx - 115968; int tt = r >> 7; int c = r & 127;
    for (int j = 0; j < 128; ++j)
      acc += Wee[(size_t)tt * 128 + j] *
             (We[(size_t)j * 384 + c] + We[(size_t)j * 384 + 128 + c] + We[(size_t)j * 384 + 256 + c]);
    mats[idx] = acc * (1.0f / 3.0f);
  }
}

// ========== stage-2a: fat-GEMM weights WABT[3l][896c][128k] + biasAB[3l][896] ==========
// cols: 0..383 qk (Wq_h@Wk_h^T); 384..767 g2 (Wq_h@M2T_h); 768..839 g34; 840..895 zero.
__global__ void prepB_kernel(const float* __restrict__ Wq, const float* __restrict__ bq,
                             const float* __restrict__ Wk, const float* __restrict__ matsAll,
                             f16* __restrict__ WABT, float* __restrict__ biasAB)
{
  int idx = blockIdx.x * 256 + threadIdx.x;
  if (idx < 344064) {                       // weights: 3 * 896 * 128
    int i = idx / 114688; int r = idx % 114688; int c = r >> 7; int k = r & 127;
    float acc = 0.f;
    if (c < 384) {
      int h = c >> 7, u = c & 127;
      const float* wq = Wq + ((size_t)i * 128 + k) * 384 + h * 128;
      const float* wk = Wk + ((size_t)i * 128 + u) * 384 + h * 128;
      for (int c2 = 0; c2 < 128; ++c2) acc += wq[c2] * wk[c2];
    } else if (c < 768) {
      int h = (c - 384) >> 7, u = (c - 384) & 127;
      const float* wq = Wq + ((size_t)i * 128 + k) * 384 + h * 128;
      const float* m2 = matsAll + (size_t)i * 132352 + h * 16384 + u;
      for (int c2 = 0; c2 < 128; ++c2) acc += wq[c2] * m2[c2 * 128];
    } else if (c < 840) {
      int h = (c - 768) / 24, tt = (c - 768) % 24;
      const float* wq = Wq + ((size_t)i * 128 + k) * 384 + h * 128;
      const float* m34 = matsAll + (size_t)i * 132352 + 49152 + h * 3072 + tt;
      for (int c2 = 0; c2 < 128; ++c2) acc += wq[c2] * m34[c2 * 24];
    }
    WABT[(size_t)i * 114688 + c * 128 + k] = (f16)acc;
  } else if (idx < 346752) {                // biases: 3 * 896
    int r = idx - 344064; int i = r / 896; int c = r % 896;
    float acc = 0.f;
    if (c < 384) {
      int h = c >> 7, u = c & 127;
      const float* bqv = bq + i * 384 + h * 128;
      const float* wk = Wk + ((size_t)i * 128 + u) * 384 + h * 128;
      for (int c2 = 0; c2 < 128; ++c2) acc += bqv[c2] * wk[c2];
    } else if (c < 768) {
      int h = (c - 384) >> 7, u = (c - 384) & 127;
      const float* bqv = bq + i * 384 + h * 128;
      const float* m2 = matsAll + (size_t)i * 132352 + h * 16384 + u;
      for (int c2 = 0; c2 < 128; ++c2) acc += bqv[c2] * m2[c2 * 128];
    } else if (c < 840) {
      int h = (c - 768) / 24, tt = (c - 768) % 24;
      const float* bqv = bq + i * 384 + h * 128;
      const float* m34 = matsAll + (size_t)i * 132352 + 49152 + h * 3072 + tt;
      for (int c2 = 0; c2 < 128; ++c2) acc += bqv[c2] * m34[c2 * 24];
    }
    biasAB[i * 896 + c] = acc;
  }
}

// ========== stage-2b: output-GEMM weights W2bigT[3l][128c][1152k] ==========
// k: 0..383 WW2(F2); 384..767 Wv(Fv); 768..839 WWg/bvec+bv(fg); 840..895 zero;
//    896..1023 Wsum0 (masked-h); 1024..1151 Ws (skip).
__global__ void prep2_kernel(const float* __restrict__ matsAll, const float* __restrict__ Wv,
                             const float* __restrict__ bv, const float* __restrict__ Ws,
                             f16* __restrict__ W2bigT)
{
  int idx = blockIdx.x * 256 + threadIdx.x;
  if (idx >= 442368) return;                // 3 * 128 * 1152
  int i = idx / 147456; int r = idx % 147456; int c = r / 1152; int k = r % 1152;
  float v = 0.f;
  if (k < 384) {
    int h = k >> 7, tt = k & 127;
    v = matsAll[(size_t)i * 132352 + 58368 + h * 16384 + tt * 128 + c];
  } else if (k < 768) {
    int h = (k - 384) >> 7, u = (k - 384) & 127;
    v = Wv[((size_t)i * 128 + u) * 384 + h * 128 + c];
  } else if (k < 840) {
    int h = (k - 768) / 24, tt = (k - 768) % 24;
    if (tt < 21)       v = matsAll[(size_t)i * 132352 + 107520 + h * 2688 + tt * 128 + c];
    else if (tt == 21) v = matsAll[(size_t)i * 132352 + 115584 + h * 128 + c]
                         + bv[i * 384 + h * 128 + c];
  } else if (k < 896) {
    v = 0.f;
  } else if (k < 1024) {
    v = matsAll[(size_t)i * 132352 + 115968 + (k - 896) * 128 + c];
  } else {
    v = Ws[((size_t)i * 128 + (k - 1024)) * 128 + c];
  }
  W2bigT[(size_t)i * 147456 + c * 1152 + k] = (f16)v;
}

// small weights: WresT [128c][128k], WctrT2 [128c][256k] with halves SWAPPED (A = [h3|h])
__global__ void wprep_kernel(const float* __restrict__ Wres, const float* __restrict__ Wctr,
                             f16* __restrict__ WresT, f16* __restrict__ WctrT2)
{
  int idx = blockIdx.x * 256 + threadIdx.x;
  if (idx < 16384) {
    int c = idx >> 7, k = idx & 127;
    WresT[idx] = (f16)Wres[k * 128 + c];
  } else if (idx < 49152) {
    int r = idx - 16384; int c = r >> 8, k = r & 255;
    float v = (k < 128) ? Wctr[(size_t)(128 + k) * 128 + c]
                        : Wctr[(size_t)(k - 128) * 128 + c];
    WctrT2[r] = (f16)v;
  }
}

// ========== attention v5: xh-interleaved gather, 2-edge unrolled, writes masked-h ==========
// nbuf [N][1024]: in 0..383 qk | 384..767 g2 | 768..839 g34
//                 out 0..383 F2 | 384..767 Fv | 768..839 fg | 896..1023 mask*h
__global__ __launch_bounds__(256) void attn_kernel(
    const f16* __restrict__ xh,     // [N][256] = [x | h]
    f16* __restrict__ nbuf,
    const int* __restrict__ rowstart,
    const int* __restrict__ srcp,
    const f16* __restrict__ dirpb,
    const f16* __restrict__ geop)
{
  const int sl = threadIdx.x & 15;
  const int n = blockIdx.x * 16 + (threadIdx.x >> 4);
  const float rsC = 0.088388347648318447f;  // 1/sqrt(128)
  f16* row = nbuf + (size_t)n * 1024;

  f16x8 qk[3], g2[3];
#pragma unroll
  for (int h = 0; h < 3; ++h) {
    qk[h] = *(const f16x8*)(row + h * 128 + sl * 8);
    g2[h] = *(const f16x8*)(row + 384 + h * 128 + sl * 8);
  }
  float g34a[3], g34c[3];
#pragma unroll
  for (int h = 0; h < 3; ++h) {
    g34a[h] = (float)row[768 + h * 24 + sl];
    g34c[h] = (sl < 8) ? (float)row[768 + h * 24 + 16 + sl] : 0.f;
  }
  float den[3] = {0.f, 0.f, 0.f};
  float F2[3][8], Fv[3][8];
#pragma unroll
  for (int h = 0; h < 3; ++h)
#pragma unroll
    for (int j = 0; j < 8; ++j) { F2[h][j] = 0.f; Fv[h][j] = 0.f; }
  float f34a[3] = {0.f, 0.f, 0.f}, f34c[3] = {0.f, 0.f, 0.f};

  const int beg = rowstart[n], end = rowstart[n + 1];
  int ii = beg;
  for (; ii + 1 < end; ii += 2) {
    const int s0 = srcp[ii], s1 = srcp[ii + 1];
    const float d0 = (float)dirpb[ii], d1 = (float)dirpb[ii + 1];
    const f16* p0 = xh + (size_t)s0 * 256 + sl * 8;
    const f16* p1 = xh + (size_t)s1 * 256 + sl * 8;
    f16x8 xv0 = *(const f16x8*)p0;
    f16x8 hv0 = *(const f16x8*)(p0 + 128);
    f16x8 xv1 = *(const f16x8*)p1;
    f16x8 hv1 = *(const f16x8*)(p1 + 128);
    const float gea0 = (float)geop[(size_t)ii * 24 + sl];
    const float geb0 = (sl < 8) ? (float)geop[(size_t)ii * 24 + 16 + sl] : 0.f;
    const float gea1 = (float)geop[(size_t)(ii + 1) * 24 + sl];
    const float geb1 = (sl < 8) ? (float)geop[(size_t)(ii + 1) * 24 + 16 + sl] : 0.f;

    float pa[6];
#pragma unroll
    for (int h = 0; h < 3; ++h) {
      pa[h]     = dot8(qk[h], xv0, 0.f) + d0 * dot8(g2[h], hv0, 0.f)
                + gea0 * g34a[h] + geb0 * g34c[h];
      pa[3 + h] = dot8(qk[h], xv1, 0.f) + d1 * dot8(g2[h], hv1, 0.f)
                + gea1 * g34a[h] + geb1 * g34c[h];
    }
#pragma unroll
    for (int off = 1; off < 16; off <<= 1) {
#pragma unroll
      for (int q = 0; q < 6; ++q) pa[q] += __shfl_xor(pa[q], off);
    }
    float w0[3], w1[3];
#pragma unroll
    for (int h = 0; h < 3; ++h) {
      w0[h] = __expf(pa[h] * rsC);
      w1[h] = __expf(pa[3 + h] * rsC);
      den[h] += w0[h] + w1[h];
    }
#pragma unroll
    for (int h = 0; h < 3; ++h) {
      const float wd0 = w0[h] * d0, wd1 = w1[h] * d1;
#pragma unroll
      for (int j = 0; j < 8; ++j) {
        F2[h][j] = fmaf(wd0, (float)hv0[j], fmaf(wd1, (float)hv1[j], F2[h][j]));
        Fv[h][j] = fmaf(w0[h], (float)xv0[j], fmaf(w1[h], (float)xv1[j], Fv[h][j]));
      }
      f34a[h] = fmaf(w0[h], gea0, fmaf(w1[h], gea1, f34a[h]));
      f34c[h] = fmaf(w0[h], geb0, fmaf(w1[h], geb1, f34c[h]));
    }
  }
  if (ii < end) {
    const int s0 = srcp[ii];
    const float d0 = (float)dirpb[ii];
    const f16* p0 = xh + (size_t)s0 * 256 + sl * 8;
    f16x8 xv0 = *(const f16x8*)p0;
    f16x8 hv0 = *(const f16x8*)(p0 + 128);
    const float gea0 = (float)geop[(size_t)ii * 24 + sl];
    const float geb0 = (sl < 8) ? (float)geop[(size_t)ii * 24 + 16 + sl] : 0.f;
    float pa[3];
#pragma unroll
    for (int h = 0; h < 3; ++h)
      pa[h] = dot8(qk[h], xv0, 0.f) + d0 * dot8(g2[h], hv0, 0.f)
            + gea0 * g34a[h] + geb0 * g34c[h];
#pragma unroll
    for (int off = 1; off < 16; off <<= 1) {
#pragma unroll
      for (int q = 0; q < 3; ++q) pa[q] += __shfl_xor(pa[q], off);
    }
#pragma unroll
    for (int h = 0; h < 3; ++h) {
      const float w = __expf(pa[h] * rsC);
      den[h] += w;
      const float wd = w * d0;
#pragma unroll
      for (int j = 0; j < 8; ++j) {
        F2[h][j] = fmaf(wd, (float)hv0[j], F2[h][j]);
        Fv[h][j] = fmaf(w, (float)xv0[j], Fv[h][j]);
      }
      f34a[h] = fmaf(w, gea0, f34a[h]);
      f34c[h] = fmaf(w, geb0, f34c[h]);
    }
  }

  float sc[3], swh[3];
#pragma unroll
  for (int h = 0; h < 3; ++h) {
    sc[h] = (1.f / 3.f) / (den[h] + 1e-16f);
    swh[h] = den[h] * sc[h];
  }
#pragma unroll
  for (int h = 0; h < 3; ++h) {
    f16x8 o1, o2;
#pragma unroll
    for (int j = 0; j < 8; ++j) {
      o1[j] = (f16)(F2[h][j] * sc[h]);
      o2[j] = (f16)(Fv[h][j] * sc[h]);
    }
    *(f16x8*)(row + h * 128 + sl * 8) = o1;
    *(f16x8*)(row + 384 + h * 128 + sl * 8) = o2;
  }
#pragma unroll
  for (int h = 0; h < 3; ++h) {
    row[768 + h * 24 + sl] = (f16)(f34a[h] * sc[h]);
    if (sl < 8) {
      float fcv = (sl == 5) ? swh[h] : f34c[h] * sc[h];
      row[768 + h * 24 + 16 + sl] = (f16)fcv;
    }
  }
  // masked h -> cols 896..1023 (feeds Wsum0 block of the output GEMM)
  f16x8 ho = *(const f16x8*)(xh + (size_t)n * 256 + 128 + sl * 8);
  if (beg >= end) {
#pragma unroll
    for (int j = 0; j < 8; ++j) ho[j] = (f16)0.f;
  }
  *(f16x8*)(row + 896 + sl * 8) = ho;
}

// ================= h f32 -> xh[N][256] = [x|h] (both halves = h initially) =================
__global__ void hconv_kernel(const float* __restrict__ src, f16* __restrict__ xh) {
  int i = blockIdx.x * 256 + threadIdx.x;
  if (i >= NN * 32) return;
  float4 a = ((const float4*)src)[i];
  f16x4 o;
  o[0] = (f16)a.x; o[1] = (f16)a.y; o[2] = (f16)a.z; o[3] = (f16)a.w;
  int r = i >> 5, c4 = i & 31;
  *(f16x4*)(xh + (size_t)r * 256 + c4 * 4) = o;
  *(f16x4*)(xh + (size_t)r * 256 + 128 + c4 * 4) = o;
}

// ================= launch =================
extern "C" void kernel_launch(void* const* d_in, const int* in_sizes, int n_in,
                              void* d_out, int out_size, void* d_ws, size_t ws_size,
                              hipStream_t stream)
{
  (void)in_sizes; (void)n_in; (void)out_size; (void)ws_size;
  const float* h    = (const float*)d_in[0];
  const float* geo  = (const float*)d_in[1];
  const float* dirw = (const float*)d_in[2];
  const int*   src  = (const int*)d_in[3];
  const int*   dst  = (const int*)d_in[4];
  const float* Wee  = (const float*)d_in[5];
  const float* bee  = (const float*)d_in[6];
  const float* Wres = (const float*)d_in[7];
  const float* bres = (const float*)d_in[8];
  const float* Wq   = (const float*)d_in[9];
  const float* bq   = (const float*)d_in[10];
  const float* Wk   = (const float*)d_in[11];
  const float* bk   = (const float*)d_in[12];  (void)bk;   // cancels in softmax
  const float* Wv   = (const float*)d_in[13];
  const float* bv   = (const float*)d_in[14];
  const float* We   = (const float*)d_in[15];
  const float* be   = (const float*)d_in[16];
  const float* Ws   = (const float*)d_in[17];
  const float* bs   = (const float*)d_in[18];
  const float* Wctr = (const float*)d_in[19];
  const float* bctr = (const float*)d_in[20];

  char* base = (char*)d_ws;
  size_t off = 0;
  auto take = [&](size_t bytes) -> char* {
    char* p = base + off;
    off += bytes;
    off = (off + 255) & ~(size_t)255;
    return p;
  };
  f16* nbuf     = (f16*)take((size_t)NN * 1024 * 2);
  f16* xh       = (f16*)take((size_t)NN * 256 * 2);
  f16* xb2      = (f16*)take((size_t)NN * 128 * 2);
  float* mats   = (float*)take((size_t)3 * 132352 * 4);
  f16* WABT     = (f16*)take((size_t)3 * 114688 * 2);
  float* biasAB = (float*)take((size_t)3 * 896 * 4);
  f16* W2bigT   = (f16*)take((size_t)3 * 147456 * 2);
  f16* WresT    = (f16*)take(16384 * 2);
  f16* WctrT2   = (f16*)take(32768 * 2);
  f16* dirpb    = (f16*)take((size_t)NE * 2);
  f16* geop     = (f16*)take((size_t)NE * 24 * 2);
  int* deg      = (int*)take((size_t)NN * 4);
  int* rowstart = (int*)take((size_t)(NN + 1) * 4);
  int* cursor   = (int*)take((size_t)NN * 4);
  int* srcp     = (int*)take((size_t)NE * 4);
  int* part     = (int*)take(256 * 4);

  // CSR by dst
  zero_int_kernel<<<(NN + 255) / 256, 256, 0, stream>>>(deg, NN);
  hist_kernel<<<(NE + 255) / 256, 256, 0, stream>>>(dst, deg);
  scanA_kernel<<<196, 256, 0, stream>>>(deg, rowstart, part);
  scanB_kernel<<<1, 256, 0, stream>>>(part, 196);
  scanC_kernel<<<196, 256, 0, stream>>>(deg, rowstart, part, cursor);
  scatter_kernel<<<(NE + 255) / 256, 256, 0, stream>>>(dst, src, dirw, geo, cursor,
                                                       srcp, dirpb, geop);
  hconv_kernel<<<6250, 256, 0, stream>>>(h, xh);
  wprep_kernel<<<192, 256, 0, stream>>>(Wres, Wctr, WresT, WctrT2);
  prep_kernel<<<dim3(518, 3), 256, 0, stream>>>(Wee, bee, We, be, mats);
  prepB_kernel<<<(346752 + 255) / 256, 256, 0, stream>>>(Wq, bq, Wk, mats, WABT, biasAB);
  prep2_kernel<<<(442368 + 255) / 256, 256, 0, stream>>>(mats, Wv, bv, Ws, W2bigT);

  // layer-0 residual: xb2 = h@Wres + bres (f16)
  hgemm_k128_kernel<<<dim3(391, 1), 256, 0, stream>>>(xh, 256, WresT, bres, xb2, 128, NN, 2);

  for (int i = 0; i < 3; ++i) {
    // fat: x @ [qk|g2|g34|0] -> nbuf cols 0..895
    hgemm_k128_kernel<<<dim3(391, 2), 256, 0, stream>>>(xh, 256, WABT + (size_t)i * 114688,
        biasAB + (size_t)i * 896, nbuf, 1024, NN, 7);
    // attention: rewrites nbuf cols 0..839, writes masked-h to 896..1023
    attn_kernel<<<3125, 256, 0, stream>>>(xh, nbuf, rowstart, srcp, dirpb, geop);
    // out: x_new = relu([F2|Fv|fg|0|mask*h| x(A2) ] @ W2big + bs + resid) -> xh x-half
    const f16* resid = (i == 0) ? xb2 : xh;
    const int ldr = (i == 0) ? 128 : 256;
    hgemm2_kernel<<<dim3(391, 1), 256, 0, stream>>>(nbuf, 1024, xh, 256, 1024,
        W2bigT + (size_t)i * 147456, 1152, bs + i * 128, nullptr, xh, 256,
        resid, ldr, NN);
  }
  // out = [h3 | h] @ WctrT2(swapped) + bctr -> d_out f32
  hgemm2_kernel<<<dim3(391, 1), 256, 0, stream>>>(xh, 256, nullptr, 256, 1 << 30,
      WctrT2, 256, bctr, (float*)d_out, nullptr, 0, nullptr, 0, NN);
}